// Round 12
// baseline (559.977 us; speedup 1.0000x reference)
//
#include <hip/hip_runtime.h>
#include <stdint.h>

// VQ argmin, bit-replicating numpy fp32 reference (see R2).
// R18: occupancy via grid. R17 pinned the stall: grid 1024 = 4 blocks/CU
// caps residency at 16 waves/CU (occ 42%); per-wave duty 0.157 (52.6%
// VALUBusy / 3.35 waves) = ~700cyc s_load latency exposed per 64-FMA row.
// VGPR=40 allows 8 waves/SIMD -- the GRID is the binding limit. Fix:
// SPLIT 4->8 -> 2048 blocks = 8 blocks/CU = 32 waves/CU; each block does
// 256 codes (4 waves x 64; h-loop deleted, SPLIT took its place). Duty
// model: 8 x 0.157 = 1.26 -> VALU saturates. Co-resident blocks still
// share s (blk>>8) -> K$ sharing kept (R16/R17: FETCH 25MB). Same fmaf
// chains; first-min tiebreak across 8 ascending slices -> absmax stays
// 1.907349e-06. B=16 D=256 H=W=32 -> n=16384 pixels; K=2048 codes.

#define D_    256
#define K_    2048
#define HW_   1024
#define MT    64      // pixels per block
#define SPLIT 8
#define KS    (K_ / SPLIT)   // 256 codes per block (4 waves x 64)
#define NPIX  16384

// numpy pairwise combine of 8 accumulators
__device__ __forceinline__ float pw8(const float r[8]) {
    float t01 = __fadd_rn(r[0], r[1]);
    float t23 = __fadd_rn(r[2], r[3]);
    float L   = __fadd_rn(t01, t23);
    float t45 = __fadd_rn(r[4], r[5]);
    float t67 = __fadd_rn(r[6], r[7]);
    float R   = __fadd_rn(t45, t67);
    return __fadd_rn(L, R);
}

// prep: blocks [0,128) transpose cb->ct; [128,136) Bn; [136,200) An
__global__ __launch_bounds__(256) void prep_k(const float* __restrict__ z,
                                              const float* __restrict__ cb,
                                              float* __restrict__ ct,
                                              float* __restrict__ An,
                                              float* __restrict__ Bn) {
    __shared__ float t[64][65];
    int tid = threadIdx.x;
    int bx  = blockIdx.x;
    if (bx < 128) {
        int k0 = (bx & 31) << 6;
        int d0 = (bx >> 5) << 6;
        #pragma unroll
        for (int it = 0; it < 4; ++it) {
            int u  = (it << 8) + tid;
            int kk = u >> 4;
            int dd = (u & 15) << 2;
            float4 v = *reinterpret_cast<const float4*>(
                cb + (size_t)(k0 + kk) * D_ + d0 + dd);
            t[kk][dd + 0] = v.x; t[kk][dd + 1] = v.y;
            t[kk][dd + 2] = v.z; t[kk][dd + 3] = v.w;
        }
        __syncthreads();
        #pragma unroll
        for (int it = 0; it < 4; ++it) {
            int u  = (it << 8) + tid;
            int dd = u >> 4;
            int kk = (u & 15) << 2;
            float4 o;
            o.x = t[kk + 0][dd]; o.y = t[kk + 1][dd];
            o.z = t[kk + 2][dd]; o.w = t[kk + 3][dd];
            *reinterpret_cast<float4*>(ct + (size_t)(d0 + dd) * K_ + k0 + kk) = o;
        }
    } else if (bx < 136) {
        int row = (bx - 128) * 256 + tid;
        const float4* p = reinterpret_cast<const float4*>(cb + (size_t)row * D_);
        float rA[8], rB[8];
        #pragma unroll
        for (int j = 0; j < 8; ++j) { rA[j] = 0.f; rB[j] = 0.f; }
        #pragma unroll
        for (int q = 0; q < 64; ++q) {
            float4 v = p[q];
            float pv[4] = {__fmul_rn(v.x, v.x), __fmul_rn(v.y, v.y),
                           __fmul_rn(v.z, v.z), __fmul_rn(v.w, v.w)};
            if (q < 32) {
                #pragma unroll
                for (int l = 0; l < 4; ++l)
                    rA[(4 * q + l) & 7] = __fadd_rn(rA[(4 * q + l) & 7], pv[l]);
            } else {
                #pragma unroll
                for (int l = 0; l < 4; ++l)
                    rB[(4 * q + l) & 7] = __fadd_rn(rB[(4 * q + l) & 7], pv[l]);
            }
        }
        Bn[row] = __fadd_rn(pw8(rA), pw8(rB));
    } else {
        int blk = bx - 136;                  // [0,64): 256 pixels each
        int b   = blk >> 2;
        int hw0 = (blk & 3) << 8;
        const float* zb = z + (size_t)b * (D_ * HW_) + hw0 + tid;
        float rA[8], rB[8];
        #pragma unroll
        for (int j = 0; j < 8; ++j) { rA[j] = 0.f; rB[j] = 0.f; }
        #pragma unroll 8
        for (int d = 0; d < 128; ++d) {      // coalesced: consecutive threads
            float v = zb[(size_t)d * HW_];
            rA[d & 7] = __fadd_rn(rA[d & 7], __fmul_rn(v, v));
        }
        #pragma unroll 8
        for (int d = 128; d < 256; ++d) {
            float v = zb[(size_t)d * HW_];
            rB[d & 7] = __fadd_rn(rB[d & 7], __fmul_rn(v, v));
        }
        An[(size_t)b * HW_ + hw0 + tid] = __fadd_rn(pw8(rA), pw8(rB));
    }
}

// main GEMM+argmin: lane=pixel, wave=64 codes; c scalar (s_load), z VMEM
__global__ __launch_bounds__(256, 2) void vq_k(const float* __restrict__ z,
                                               const float* __restrict__ ct,
                                               const float* __restrict__ An,
                                               const float* __restrict__ Bn,
                                               float* __restrict__ pscore,
                                               int* __restrict__ pidx) {
    __shared__ float rs[256];
    __shared__ int   ri[256];

    const int tid  = threadIdx.x;
    const int lane = tid & 63;                    // pixel within block
    const int wu   = __builtin_amdgcn_readfirstlane(tid >> 6);  // wave [0,4)
    const int blk  = blockIdx.x;
    const int p    = blk & 255;                   // pixel-block [0,256) (fast)
    const int s    = blk >> 8;                    // K-split slice [0,8) (slow)
    const int b      = p >> 4;
    const int hwbase = (p & 15) << 6;

    const float* zp = z + (size_t)b * (D_ * HW_) + hwbase + lane;
    const float an  = An[(size_t)b * HW_ + hwbase + lane];

    const int code0 = s * KS + (wu << 6);         // this wave's 64 codes
    const float* cp = ct + code0;                 // row d at cp + d*K_ (uniform)

    float acc[64];
    #pragma unroll
    for (int j = 0; j < 64; ++j) acc[j] = 0.f;

    // ascending-d fmaf chain per code — bit-matches sgemm
    for (int d = 0; d < D_; ++d) {
        float zv = zp[(size_t)d * HW_];           // coalesced VMEM (256B/wave)
        const float* cr = cp + (size_t)d * K_;    // uniform -> s_load
        #pragma unroll
        for (int j = 0; j < 64; ++j)
            acc[j] = fmaf(zv, cr[j], acc[j]);
    }

    // per-lane argmin over this wave's 64 codes (ascending -> first-min)
    const float* bp = Bn + code0;                 // uniform -> s_load
    float best = 1e30f; int bidx = 0;
    #pragma unroll
    for (int j = 0; j < 64; ++j) {
        float sc = __fsub_rn(__fadd_rn(an, bp[j]),
                             __fmul_rn(2.0f, acc[j]));
        if (sc < best) { best = sc; bidx = code0 + j; }
    }

    // cross-wave merge (ascending wave order keeps lowest-index tiebreak)
    rs[(wu << 6) + lane] = best;
    ri[(wu << 6) + lane] = bidx;
    __syncthreads();
    if (tid < MT) {
        float bb = rs[tid]; int bx = ri[tid];
        #pragma unroll
        for (int t = 1; t < 4; ++t) {
            float sv = rs[(t << 6) + tid];
            int   ix = ri[(t << 6) + tid];
            if (sv < bb || (sv == bb && ix < bx)) { bb = sv; bx = ix; }
        }
        int g = b * HW_ + hwbase + tid;
        pscore[s * NPIX + g] = bb;
        pidx[s * NPIX + g]   = bx;
    }
}

// merge SPLIT partials (first-min tiebreak) + gather output
__global__ __launch_bounds__(256) void fin_k(const float* __restrict__ cb,
                                             const float* __restrict__ pscore,
                                             const int* __restrict__ pidx,
                                             float* __restrict__ out) {
    __shared__ int idxs[MT];
    int tid = threadIdx.x;
    int p   = blockIdx.x;               // [0,256)
    int b      = p >> 4;
    int hwbase = (p & 15) << 6;
    if (tid < MT) {
        int g = b * HW_ + hwbase + tid;
        float best = pscore[g];
        int   bidx = pidx[g];
        #pragma unroll
        for (int s = 1; s < SPLIT; ++s) {
            float sv = pscore[s * NPIX + g];
            int   ix = pidx[s * NPIX + g];
            if (sv < best || (sv == best && ix < bidx)) { best = sv; bidx = ix; }
        }
        idxs[tid] = bidx;
    }
    __syncthreads();
    float* obase = out + (size_t)b * (D_ * HW_) + hwbase;
    #pragma unroll
    for (int it = 0; it < 16; ++it) {
        int u  = (it << 8) + tid;
        int dd = u >> 4;                // [0,256)
        int m4 = u & 15;
        int i0 = idxs[(m4 << 2) + 0];
        int i1 = idxs[(m4 << 2) + 1];
        int i2 = idxs[(m4 << 2) + 2];
        int i3 = idxs[(m4 << 2) + 3];
        float4 o;
        o.x = cb[(size_t)i0 * D_ + dd];
        o.y = cb[(size_t)i1 * D_ + dd];
        o.z = cb[(size_t)i2 * D_ + dd];
        o.w = cb[(size_t)i3 * D_ + dd];
        *reinterpret_cast<float4*>(obase + (size_t)dd * HW_ + (m4 << 2)) = o;
    }
}

extern "C" void kernel_launch(void* const* d_in, const int* in_sizes, int n_in,
                              void* d_out, int out_size, void* d_ws, size_t ws_size,
                              hipStream_t stream) {
    const float* z  = (const float*)d_in[0];   // 16*256*32*32
    const float* cb = (const float*)d_in[1];   // 2048*256
    float* pscore = (float*)d_ws;                       // 8*16384
    int*   pidx   = (int*)(pscore + SPLIT * NPIX);      // 8*16384
    float* An     = (float*)(pidx + SPLIT * NPIX);      // 16384
    float* Bn     = An + NPIX;                          // 2048
    float* ct     = Bn + K_;                            // 256*2048 (2 MB)
    float* out    = (float*)d_out;

    prep_k<<<dim3(200), dim3(256), 0, stream>>>(z, cb, ct, An, Bn);
    vq_k<<<dim3(256 * SPLIT), dim3(256), 0, stream>>>(z, ct, An, Bn, pscore, pidx);
    fin_k<<<dim3(256), dim3(256), 0, stream>>>(cb, pscore, pidx, out);
}

// Round 13
// 277.081 us; speedup vs baseline: 2.0210x; 2.0210x over previous
//
#include <hip/hip_runtime.h>
#include <stdint.h>

// VQ argmin, bit-replicating numpy fp32 reference (see R2).
// R19: revert to R12 (session best: vq_k 202us, total 281us) + decode swap.
// R13-R18 post-mortems: KT=8 added barrier stalls (214); the scalar-codebook
// path bottoms at ~230 when the compiler pipelines s_loads and regresses
// 2-3x when it doesn't (SGPR 112->48 on innocuous edits) -- abandoned.
// The one transferable finding: decode p=fast/s=slow (R16/R17) makes
// co-resident blocks share the SAME 512KB ct slice (FETCH 70->25MB).
// R12's decode shared z (64KB) instead; swapping shares the big stream ->
// better L2 hit for the per-phase DMA the barrier drains. Everything else
// is R12 verbatim: jt=16 (two 8-code groups at tn*8, 256+tn*8), KT=16,
// v2f pk_fma accs, single flush. BIT-EXACT (absmax must stay 1.907349e-06).
// B=16 D=256 H=W=32 -> n=16384 pixels; K=2048 codes.

#define D_    256
#define K_    2048
#define HW_   1024
#define MT    64      // pixels per block
#define KT    16      // dims per phase
#define SPLIT 4
#define KS    (K_ / SPLIT)   // 512 codes per block = one acc chunk
#define CST   512     // c row stride (floats); 2-way banks on read = free
#define BUFSZ (KT * MT + KT * CST)   // 9216 floats per buffer
#define NPH   (D_ / KT)              // 16 phases (each dim staged once)
#define NPIX  16384

typedef float v2f __attribute__((ext_vector_type(2)));

// global -> LDS direct DMA, 16 B per lane, wave-uniform LDS base (CK-style casts)
__device__ __forceinline__ void gload16(const float* g, float* l) {
    auto* gp = reinterpret_cast<const __attribute__((address_space(1))) uint32_t*>(
        reinterpret_cast<uintptr_t>(g));
    auto* lp = reinterpret_cast<__attribute__((address_space(3))) uint32_t*>(
        reinterpret_cast<uintptr_t>(l));
    __builtin_amdgcn_global_load_lds(gp, lp, 16, 0, 0);
}

// numpy pairwise combine of 8 accumulators
__device__ __forceinline__ float pw8(const float r[8]) {
    float t01 = __fadd_rn(r[0], r[1]);
    float t23 = __fadd_rn(r[2], r[3]);
    float L   = __fadd_rn(t01, t23);
    float t45 = __fadd_rn(r[4], r[5]);
    float t67 = __fadd_rn(r[6], r[7]);
    float R   = __fadd_rn(t45, t67);
    return __fadd_rn(L, R);
}

// prep: blocks [0,128) transpose cb->ct; [128,136) Bn; [136,200) An
__global__ __launch_bounds__(256) void prep_k(const float* __restrict__ z,
                                              const float* __restrict__ cb,
                                              float* __restrict__ ct,
                                              float* __restrict__ An,
                                              float* __restrict__ Bn) {
    __shared__ float t[64][65];
    int tid = threadIdx.x;
    int bx  = blockIdx.x;
    if (bx < 128) {
        int k0 = (bx & 31) << 6;
        int d0 = (bx >> 5) << 6;
        #pragma unroll
        for (int it = 0; it < 4; ++it) {
            int u  = (it << 8) + tid;
            int kk = u >> 4;
            int dd = (u & 15) << 2;
            float4 v = *reinterpret_cast<const float4*>(
                cb + (size_t)(k0 + kk) * D_ + d0 + dd);
            t[kk][dd + 0] = v.x; t[kk][dd + 1] = v.y;
            t[kk][dd + 2] = v.z; t[kk][dd + 3] = v.w;
        }
        __syncthreads();
        #pragma unroll
        for (int it = 0; it < 4; ++it) {
            int u  = (it << 8) + tid;
            int dd = u >> 4;
            int kk = (u & 15) << 2;
            float4 o;
            o.x = t[kk + 0][dd]; o.y = t[kk + 1][dd];
            o.z = t[kk + 2][dd]; o.w = t[kk + 3][dd];
            *reinterpret_cast<float4*>(ct + (size_t)(d0 + dd) * K_ + k0 + kk) = o;
        }
    } else if (bx < 136) {
        int row = (bx - 128) * 256 + tid;
        const float4* p = reinterpret_cast<const float4*>(cb + (size_t)row * D_);
        float rA[8], rB[8];
        #pragma unroll
        for (int j = 0; j < 8; ++j) { rA[j] = 0.f; rB[j] = 0.f; }
        #pragma unroll
        for (int q = 0; q < 64; ++q) {
            float4 v = p[q];
            float pv[4] = {__fmul_rn(v.x, v.x), __fmul_rn(v.y, v.y),
                           __fmul_rn(v.z, v.z), __fmul_rn(v.w, v.w)};
            if (q < 32) {
                #pragma unroll
                for (int l = 0; l < 4; ++l)
                    rA[(4 * q + l) & 7] = __fadd_rn(rA[(4 * q + l) & 7], pv[l]);
            } else {
                #pragma unroll
                for (int l = 0; l < 4; ++l)
                    rB[(4 * q + l) & 7] = __fadd_rn(rB[(4 * q + l) & 7], pv[l]);
            }
        }
        Bn[row] = __fadd_rn(pw8(rA), pw8(rB));
    } else {
        int blk = bx - 136;                  // [0,64): 256 pixels each
        int b   = blk >> 2;
        int hw0 = (blk & 3) << 8;
        const float* zb = z + (size_t)b * (D_ * HW_) + hw0 + tid;
        float rA[8], rB[8];
        #pragma unroll
        for (int j = 0; j < 8; ++j) { rA[j] = 0.f; rB[j] = 0.f; }
        #pragma unroll 8
        for (int d = 0; d < 128; ++d) {      // coalesced: consecutive threads
            float v = zb[(size_t)d * HW_];
            rA[d & 7] = __fadd_rn(rA[d & 7], __fmul_rn(v, v));
        }
        #pragma unroll 8
        for (int d = 128; d < 256; ++d) {
            float v = zb[(size_t)d * HW_];
            rB[d & 7] = __fadd_rn(rB[d & 7], __fmul_rn(v, v));
        }
        An[(size_t)b * HW_ + hw0 + tid] = __fadd_rn(pw8(rA), pw8(rB));
    }
}

// main GEMM+argmin: LDS double-buffered via global_load_lds DMA, pk_fma math
__global__ __launch_bounds__(256, 2) void vq_k(const float* __restrict__ z,
                                               const float* __restrict__ ct,
                                               const float* __restrict__ An,
                                               const float* __restrict__ Bn,
                                               float* __restrict__ pscore,
                                               int* __restrict__ pidx) {
    __shared__ float smem[2 * BUFSZ];            // 73728 B -> 2 blocks/CU
    float* rs = smem;                            // aliased for reduce
    int*   ri = (int*)(smem + MT * 33);

    const int tid  = threadIdx.x;
    const int lane = tid & 63;
    const int w    = tid >> 6;                   // wave id [0,4)
    const int tn   = (tid & 7) | (w << 3);       // [0,32) code-group
    const int tm   = (tid >> 3) & 7;             // [0,8)  pixel-group
    const int blk  = blockIdx.x;
    const int p    = blk & 255;                  // pixel-block [0,256) (fast)
    const int s    = blk >> 8;                   // K-split slice (slow)
    const int b      = p >> 4;
    const int hwbase = (p & 15) << 6;
    const float* zbase = z + (size_t)b * (D_ * HW_) + hwbase;
    const float* ctS   = ct + s * KS;

    // per-lane DMA source bases (z: lane covers row 4w+(lane>>4), col (lane&15)*4)
    const float* zsrc = zbase + (size_t)((w << 2) + (lane >> 4)) * HW_
                              + ((lane & 15) << 2);

    float bs[8]; int bi[8];
    #pragma unroll
    for (int i = 0; i < 8; ++i) { bs[i] = 1e30f; bi[i] = 0; }
    // acc[i][q]: q<4 -> codes tn*8+{2q,2q+1}; q>=4 -> codes 256+tn*8+{2(q-4),...}
    v2f acc[8][8];
    #pragma unroll
    for (int i = 0; i < 8; ++i)
        #pragma unroll
        for (int q = 0; q < 8; ++q) acc[i][q] = (v2f){0.f, 0.f};

    // stage phase ph into buf[ph&1]: 1 z-DMA + 8 c-DMAs per wave
    #define STAGE(ph)                                                         \
        do {                                                                  \
            int buf_ = (ph) & 1, kc_ = (ph);                                  \
            float* zb_ = smem + buf_ * BUFSZ;                                 \
            float* cb_ = zb_ + KT * MT;                                       \
            gload16(zsrc + (size_t)kc_ * (KT * HW_), zb_ + (w << 2) * MT);    \
            _Pragma("unroll")                                                 \
            for (int r = 0; r < 4; ++r) {                                     \
                int row = (w << 2) + r;                                       \
                const float* src_ = ctS + (size_t)((kc_ << 4) + row) * K_     \
                                        + (lane << 2);                        \
                gload16(src_,       cb_ + row * CST);                         \
                gload16(src_ + 256, cb_ + row * CST + 256);                   \
            }                                                                 \
        } while (0)

    STAGE(0);

    for (int ph = 0; ph < NPH; ++ph) {
        __syncthreads();          // drains phase-ph DMA (issued 1 phase ago)
        if (ph < NPH - 1) STAGE(ph + 1);  // into other buffer (safe: read at ph-1)
        const float* zb_ = smem + (ph & 1) * BUFSZ;
        const float* cb_ = zb_ + KT * MT;
        // ascending-k per-accumulator fma chains — bit-match sgemm
        #pragma unroll
        for (int d = 0; d < KT; ++d) {
            const float* zr = zb_ + d * MT + (tm << 3);
            float4 a0 = *reinterpret_cast<const float4*>(zr);
            float4 a1 = *reinterpret_cast<const float4*>(zr + 4);
            const float* cr = cb_ + d * CST + (tn << 3);
            float4 b0 = *reinterpret_cast<const float4*>(cr);
            float4 b1 = *reinterpret_cast<const float4*>(cr + 4);
            float4 b2 = *reinterpret_cast<const float4*>(cr + 256);
            float4 b3 = *reinterpret_cast<const float4*>(cr + 260);
            v2f bp0 = {b0.x, b0.y}, bp1 = {b0.z, b0.w};
            v2f bp2 = {b1.x, b1.y}, bp3 = {b1.z, b1.w};
            v2f bp4 = {b2.x, b2.y}, bp5 = {b2.z, b2.w};
            v2f bp6 = {b3.x, b3.y}, bp7 = {b3.z, b3.w};
            float az[8] = {a0.x, a0.y, a0.z, a0.w, a1.x, a1.y, a1.z, a1.w};
            #pragma unroll
            for (int i = 0; i < 8; ++i) {
                v2f ai = {az[i], az[i]};
                acc[i][0] = __builtin_elementwise_fma(ai, bp0, acc[i][0]);
                acc[i][1] = __builtin_elementwise_fma(ai, bp1, acc[i][1]);
                acc[i][2] = __builtin_elementwise_fma(ai, bp2, acc[i][2]);
                acc[i][3] = __builtin_elementwise_fma(ai, bp3, acc[i][3]);
                acc[i][4] = __builtin_elementwise_fma(ai, bp4, acc[i][4]);
                acc[i][5] = __builtin_elementwise_fma(ai, bp5, acc[i][5]);
                acc[i][6] = __builtin_elementwise_fma(ai, bp6, acc[i][6]);
                acc[i][7] = __builtin_elementwise_fma(ai, bp7, acc[i][7]);
            }
        }
    }
    #undef STAGE

    // single argmin flush over all 512 codes (ascending ng per thread)
    #pragma unroll
    for (int h = 0; h < 2; ++h) {
        #pragma unroll
        for (int jj = 0; jj < 8; ++jj) {
            int q  = (h << 2) + (jj >> 1);
            int ng = s * KS + h * 256 + (tn << 3) + jj;
            float bn = Bn[ng];
            #pragma unroll
            for (int i = 0; i < 8; ++i) {
                float an = An[(size_t)b * HW_ + hwbase + (tm << 3) + i];
                float sc = __fsub_rn(__fadd_rn(an, bn),
                                     __fmul_rn(2.0f, acc[i][q][jj & 1]));
                if (sc < bs[i]) { bs[i] = sc; bi[i] = ng; }
            }
        }
    }

    __syncthreads();   // protect smem before aliasing
    #pragma unroll
    for (int i = 0; i < 8; ++i) {
        int m = (tm << 3) + i;
        rs[m * 33 + tn] = bs[i];
        ri[m * 33 + tn] = bi[i];
    }
    __syncthreads();
    if (tid < MT) {
        int   m    = tid;
        float best = rs[m * 33];
        int   bidx = ri[m * 33];
        for (int t = 1; t < 32; ++t) {
            float sv = rs[m * 33 + t];
            int   ix = ri[m * 33 + t];
            if (sv < best || (sv == best && ix < bidx)) { best = sv; bidx = ix; }
        }
        int g = b * HW_ + hwbase + m;
        pscore[s * NPIX + g] = best;
        pidx[s * NPIX + g]   = bidx;
    }
}

// merge SPLIT partials (first-min tiebreak) + gather output
__global__ __launch_bounds__(256) void fin_k(const float* __restrict__ cb,
                                             const float* __restrict__ pscore,
                                             const int* __restrict__ pidx,
                                             float* __restrict__ out) {
    __shared__ int idxs[MT];
    int tid = threadIdx.x;
    int p   = blockIdx.x;               // [0,256)
    int b      = p >> 4;
    int hwbase = (p & 15) << 6;
    if (tid < MT) {
        int g = b * HW_ + hwbase + tid;
        float best = pscore[g];
        int   bidx = pidx[g];
        #pragma unroll
        for (int s = 1; s < SPLIT; ++s) {
            float sv = pscore[s * NPIX + g];
            int   ix = pidx[s * NPIX + g];
            if (sv < best || (sv == best && ix < bidx)) { best = sv; bidx = ix; }
        }
        idxs[tid] = bidx;
    }
    __syncthreads();
    float* obase = out + (size_t)b * (D_ * HW_) + hwbase;
    #pragma unroll
    for (int it = 0; it < 16; ++it) {
        int u  = (it << 8) + tid;
        int dd = u >> 4;                // [0,256)
        int m4 = u & 15;
        int i0 = idxs[(m4 << 2) + 0];
        int i1 = idxs[(m4 << 2) + 1];
        int i2 = idxs[(m4 << 2) + 2];
        int i3 = idxs[(m4 << 2) + 3];
        float4 o;
        o.x = cb[(size_t)i0 * D_ + dd];
        o.y = cb[(size_t)i1 * D_ + dd];
        o.z = cb[(size_t)i2 * D_ + dd];
        o.w = cb[(size_t)i3 * D_ + dd];
        *reinterpret_cast<float4*>(obase + (size_t)dd * HW_ + (m4 << 2)) = o;
    }
}

extern "C" void kernel_launch(void* const* d_in, const int* in_sizes, int n_in,
                              void* d_out, int out_size, void* d_ws, size_t ws_size,
                              hipStream_t stream) {
    const float* z  = (const float*)d_in[0];   // 16*256*32*32
    const float* cb = (const float*)d_in[1];   // 2048*256
    float* pscore = (float*)d_ws;                       // 4*16384
    int*   pidx   = (int*)(pscore + SPLIT * NPIX);      // 4*16384
    float* An     = (float*)(pidx + SPLIT * NPIX);      // 16384
    float* Bn     = An + NPIX;                          // 2048
    float* ct     = Bn + K_;                            // 256*2048 (2 MB)
    float* out    = (float*)d_out;

    prep_k<<<dim3(200), dim3(256), 0, stream>>>(z, cb, ct, An, Bn);
    vq_k<<<dim3(256 * SPLIT), dim3(256), 0, stream>>>(z, ct, An, Bn, pscore, pidx);
    fin_k<<<dim3(256), dim3(256), 0, stream>>>(cb, pscore, pidx, out);
}

// Round 14
// 275.148 us; speedup vs baseline: 2.0352x; 1.0070x over previous
//
#include <hip/hip_runtime.h>
#include <stdint.h>

// VQ argmin, bit-replicating numpy fp32 reference (see R2).
// R20: wave density. R19 (best: vq_k 200us) has LDS ~123us + VALU ~140us
// with ~60us uncovered stall at 2 waves/SIMD (73728B -> 2 blocks/CU x 4
// waves). Fix: 8-wave 512-thread blocks at MT=128 pixels -- per-thread tile
// (8 pix x 16 codes) and inner loop UNCHANGED, tn=tid&31, tm=tid>>5.
// LDS = 2*(16*128+16*512)*4 = 81920B -> exactly 2 blocks/CU (163840 =
// 160KiB) -> 16 waves/CU = 4 waves/SIMD at the same total LDS traffic;
// DMAs/wave/phase 9->5. Grid 512 = 1 pass, no tail. Decode p=fast/s=slow
// kept (FETCH 16.6MB). Same ascending-d chains, same flush/tiebreak ->
// BIT-EXACT (absmax must stay 1.907349e-06).
// B=16 D=256 H=W=32 -> n=16384 pixels; K=2048 codes.

#define D_    256
#define K_    2048
#define HW_   1024
#define MT    128     // pixels per block (8 waves)
#define KT    16      // dims per phase
#define SPLIT 4
#define KS    (K_ / SPLIT)   // 512 codes per block = one acc chunk
#define CST   512     // c row stride (floats)
#define BUFSZ (KT * MT + KT * CST)   // 10240 floats per buffer
#define NPH   (D_ / KT)              // 16 phases (each dim staged once)
#define NPIX  16384

typedef float v2f __attribute__((ext_vector_type(2)));

// global -> LDS direct DMA, 16 B per lane, wave-uniform LDS base (CK-style casts)
__device__ __forceinline__ void gload16(const float* g, float* l) {
    auto* gp = reinterpret_cast<const __attribute__((address_space(1))) uint32_t*>(
        reinterpret_cast<uintptr_t>(g));
    auto* lp = reinterpret_cast<__attribute__((address_space(3))) uint32_t*>(
        reinterpret_cast<uintptr_t>(l));
    __builtin_amdgcn_global_load_lds(gp, lp, 16, 0, 0);
}

// numpy pairwise combine of 8 accumulators
__device__ __forceinline__ float pw8(const float r[8]) {
    float t01 = __fadd_rn(r[0], r[1]);
    float t23 = __fadd_rn(r[2], r[3]);
    float L   = __fadd_rn(t01, t23);
    float t45 = __fadd_rn(r[4], r[5]);
    float t67 = __fadd_rn(r[6], r[7]);
    float R   = __fadd_rn(t45, t67);
    return __fadd_rn(L, R);
}

// prep: blocks [0,128) transpose cb->ct; [128,136) Bn; [136,200) An
__global__ __launch_bounds__(256) void prep_k(const float* __restrict__ z,
                                              const float* __restrict__ cb,
                                              float* __restrict__ ct,
                                              float* __restrict__ An,
                                              float* __restrict__ Bn) {
    __shared__ float t[64][65];
    int tid = threadIdx.x;
    int bx  = blockIdx.x;
    if (bx < 128) {
        int k0 = (bx & 31) << 6;
        int d0 = (bx >> 5) << 6;
        #pragma unroll
        for (int it = 0; it < 4; ++it) {
            int u  = (it << 8) + tid;
            int kk = u >> 4;
            int dd = (u & 15) << 2;
            float4 v = *reinterpret_cast<const float4*>(
                cb + (size_t)(k0 + kk) * D_ + d0 + dd);
            t[kk][dd + 0] = v.x; t[kk][dd + 1] = v.y;
            t[kk][dd + 2] = v.z; t[kk][dd + 3] = v.w;
        }
        __syncthreads();
        #pragma unroll
        for (int it = 0; it < 4; ++it) {
            int u  = (it << 8) + tid;
            int dd = u >> 4;
            int kk = (u & 15) << 2;
            float4 o;
            o.x = t[kk + 0][dd]; o.y = t[kk + 1][dd];
            o.z = t[kk + 2][dd]; o.w = t[kk + 3][dd];
            *reinterpret_cast<float4*>(ct + (size_t)(d0 + dd) * K_ + k0 + kk) = o;
        }
    } else if (bx < 136) {
        int row = (bx - 128) * 256 + tid;
        const float4* p = reinterpret_cast<const float4*>(cb + (size_t)row * D_);
        float rA[8], rB[8];
        #pragma unroll
        for (int j = 0; j < 8; ++j) { rA[j] = 0.f; rB[j] = 0.f; }
        #pragma unroll
        for (int q = 0; q < 64; ++q) {
            float4 v = p[q];
            float pv[4] = {__fmul_rn(v.x, v.x), __fmul_rn(v.y, v.y),
                           __fmul_rn(v.z, v.z), __fmul_rn(v.w, v.w)};
            if (q < 32) {
                #pragma unroll
                for (int l = 0; l < 4; ++l)
                    rA[(4 * q + l) & 7] = __fadd_rn(rA[(4 * q + l) & 7], pv[l]);
            } else {
                #pragma unroll
                for (int l = 0; l < 4; ++l)
                    rB[(4 * q + l) & 7] = __fadd_rn(rB[(4 * q + l) & 7], pv[l]);
            }
        }
        Bn[row] = __fadd_rn(pw8(rA), pw8(rB));
    } else {
        int blk = bx - 136;                  // [0,64): 256 pixels each
        int b   = blk >> 2;
        int hw0 = (blk & 3) << 8;
        const float* zb = z + (size_t)b * (D_ * HW_) + hw0 + tid;
        float rA[8], rB[8];
        #pragma unroll
        for (int j = 0; j < 8; ++j) { rA[j] = 0.f; rB[j] = 0.f; }
        #pragma unroll 8
        for (int d = 0; d < 128; ++d) {      // coalesced: consecutive threads
            float v = zb[(size_t)d * HW_];
            rA[d & 7] = __fadd_rn(rA[d & 7], __fmul_rn(v, v));
        }
        #pragma unroll 8
        for (int d = 128; d < 256; ++d) {
            float v = zb[(size_t)d * HW_];
            rB[d & 7] = __fadd_rn(rB[d & 7], __fmul_rn(v, v));
        }
        An[(size_t)b * HW_ + hw0 + tid] = __fadd_rn(pw8(rA), pw8(rB));
    }
}

// main GEMM+argmin: 8-wave blocks, LDS double-buffered DMA, pk_fma math
__global__ __launch_bounds__(512, 2) void vq_k(const float* __restrict__ z,
                                               const float* __restrict__ ct,
                                               const float* __restrict__ An,
                                               const float* __restrict__ Bn,
                                               float* __restrict__ pscore,
                                               int* __restrict__ pidx) {
    __shared__ float smem[2 * BUFSZ];            // 81920 B -> 2 blocks/CU
    float* rs = smem;                            // aliased for reduce
    int*   ri = (int*)(smem + MT * 33);

    const int tid  = threadIdx.x;
    const int lane = tid & 63;
    const int w    = tid >> 6;                   // wave id [0,8)
    const int tn   = tid & 31;                   // [0,32) code-group
    const int tm   = tid >> 5;                   // [0,16) pixel-group
    const int blk  = blockIdx.x;
    const int p    = blk & 127;                  // pixel-block [0,128) (fast)
    const int s    = blk >> 7;                   // K-split slice (slow)
    const int b      = p >> 3;
    const int hwbase = (p & 7) << 7;             // 128 pixels per block
    const float* zbase = z + (size_t)b * (D_ * HW_) + hwbase;
    const float* ctS   = ct + s * KS;

    // z DMA: wave w stages phase-rows 2w,2w+1; lane covers row 2w+(lane>>5),
    // col (lane&31)*4
    const float* zsrc = zbase + (size_t)((w << 1) + (lane >> 5)) * HW_
                              + ((lane & 31) << 2);

    float bs[8]; int bi[8];
    #pragma unroll
    for (int i = 0; i < 8; ++i) { bs[i] = 1e30f; bi[i] = 0; }
    // acc[i][q]: q<4 -> codes tn*8+{2q,2q+1}; q>=4 -> codes 256+tn*8+{2(q-4),...}
    v2f acc[8][8];
    #pragma unroll
    for (int i = 0; i < 8; ++i)
        #pragma unroll
        for (int q = 0; q < 8; ++q) acc[i][q] = (v2f){0.f, 0.f};

    // stage phase ph into buf[ph&1]: per wave 1 z-DMA + 4 c-half-row DMAs
    #define STAGE(ph)                                                         \
        do {                                                                  \
            int buf_ = (ph) & 1, kc_ = (ph);                                  \
            float* zb_ = smem + buf_ * BUFSZ;                                 \
            float* cb_ = zb_ + KT * MT;                                       \
            gload16(zsrc + (size_t)(kc_ << 4) * HW_, zb_ + (w << 8));         \
            _Pragma("unroll")                                                 \
            for (int r = 0; r < 4; ++r) {                                     \
                int row  = (w << 1) + (r >> 1);                               \
                int half = (r & 1) << 8;                                      \
                gload16(ctS + (size_t)((kc_ << 4) + row) * K_ + half          \
                            + (lane << 2),                                    \
                        cb_ + row * CST + half);                              \
            }                                                                 \
        } while (0)

    STAGE(0);

    for (int ph = 0; ph < NPH; ++ph) {
        __syncthreads();          // drains phase-ph DMA (issued 1 phase ago)
        if (ph < NPH - 1) STAGE(ph + 1);  // into other buffer (safe: read at ph-1)
        const float* zb_ = smem + (ph & 1) * BUFSZ;
        const float* cb_ = zb_ + KT * MT;
        // ascending-k per-accumulator fma chains — bit-match sgemm
        #pragma unroll
        for (int d = 0; d < KT; ++d) {
            const float* zr = zb_ + d * MT + (tm << 3);
            float4 a0 = *reinterpret_cast<const float4*>(zr);
            float4 a1 = *reinterpret_cast<const float4*>(zr + 4);
            const float* cr = cb_ + d * CST + (tn << 3);
            float4 b0 = *reinterpret_cast<const float4*>(cr);
            float4 b1 = *reinterpret_cast<const float4*>(cr + 4);
            float4 b2 = *reinterpret_cast<const float4*>(cr + 256);
            float4 b3 = *reinterpret_cast<const float4*>(cr + 260);
            v2f bp0 = {b0.x, b0.y}, bp1 = {b0.z, b0.w};
            v2f bp2 = {b1.x, b1.y}, bp3 = {b1.z, b1.w};
            v2f bp4 = {b2.x, b2.y}, bp5 = {b2.z, b2.w};
            v2f bp6 = {b3.x, b3.y}, bp7 = {b3.z, b3.w};
            float az[8] = {a0.x, a0.y, a0.z, a0.w, a1.x, a1.y, a1.z, a1.w};
            #pragma unroll
            for (int i = 0; i < 8; ++i) {
                v2f ai = {az[i], az[i]};
                acc[i][0] = __builtin_elementwise_fma(ai, bp0, acc[i][0]);
                acc[i][1] = __builtin_elementwise_fma(ai, bp1, acc[i][1]);
                acc[i][2] = __builtin_elementwise_fma(ai, bp2, acc[i][2]);
                acc[i][3] = __builtin_elementwise_fma(ai, bp3, acc[i][3]);
                acc[i][4] = __builtin_elementwise_fma(ai, bp4, acc[i][4]);
                acc[i][5] = __builtin_elementwise_fma(ai, bp5, acc[i][5]);
                acc[i][6] = __builtin_elementwise_fma(ai, bp6, acc[i][6]);
                acc[i][7] = __builtin_elementwise_fma(ai, bp7, acc[i][7]);
            }
        }
    }
    #undef STAGE

    // single argmin flush over all 512 codes (ascending ng per thread)
    #pragma unroll
    for (int h = 0; h < 2; ++h) {
        #pragma unroll
        for (int jj = 0; jj < 8; ++jj) {
            int q  = (h << 2) + (jj >> 1);
            int ng = s * KS + h * 256 + (tn << 3) + jj;
            float bn = Bn[ng];
            #pragma unroll
            for (int i = 0; i < 8; ++i) {
                float an = An[(size_t)b * HW_ + hwbase + (tm << 3) + i];
                float sc = __fsub_rn(__fadd_rn(an, bn),
                                     __fmul_rn(2.0f, acc[i][q][jj & 1]));
                if (sc < bs[i]) { bs[i] = sc; bi[i] = ng; }
            }
        }
    }

    __syncthreads();   // protect smem before aliasing
    #pragma unroll
    for (int i = 0; i < 8; ++i) {
        int m = (tm << 3) + i;
        rs[m * 33 + tn] = bs[i];
        ri[m * 33 + tn] = bi[i];
    }
    __syncthreads();
    if (tid < MT) {
        int   m    = tid;
        float best = rs[m * 33];
        int   bidx = ri[m * 33];
        for (int t = 1; t < 32; ++t) {
            float sv = rs[m * 33 + t];
            int   ix = ri[m * 33 + t];
            if (sv < best || (sv == best && ix < bidx)) { best = sv; bidx = ix; }
        }
        int g = b * HW_ + hwbase + m;
        pscore[s * NPIX + g] = best;
        pidx[s * NPIX + g]   = bidx;
    }
}

// merge SPLIT partials (first-min tiebreak) + gather output
__global__ __launch_bounds__(256) void fin_k(const float* __restrict__ cb,
                                             const float* __restrict__ pscore,
                                             const int* __restrict__ pidx,
                                             float* __restrict__ out) {
    __shared__ int idxs[64];
    int tid = threadIdx.x;
    int p   = blockIdx.x;               // [0,256)
    int b      = p >> 4;
    int hwbase = (p & 15) << 6;
    if (tid < 64) {
        int g = b * HW_ + hwbase + tid;
        float best = pscore[g];
        int   bidx = pidx[g];
        #pragma unroll
        for (int s = 1; s < SPLIT; ++s) {
            float sv = pscore[s * NPIX + g];
            int   ix = pidx[s * NPIX + g];
            if (sv < best || (sv == best && ix < bidx)) { best = sv; bidx = ix; }
        }
        idxs[tid] = bidx;
    }
    __syncthreads();
    float* obase = out + (size_t)b * (D_ * HW_) + hwbase;
    #pragma unroll
    for (int it = 0; it < 16; ++it) {
        int u  = (it << 8) + tid;
        int dd = u >> 4;                // [0,256)
        int m4 = u & 15;
        int i0 = idxs[(m4 << 2) + 0];
        int i1 = idxs[(m4 << 2) + 1];
        int i2 = idxs[(m4 << 2) + 2];
        int i3 = idxs[(m4 << 2) + 3];
        float4 o;
        o.x = cb[(size_t)i0 * D_ + dd];
        o.y = cb[(size_t)i1 * D_ + dd];
        o.z = cb[(size_t)i2 * D_ + dd];
        o.w = cb[(size_t)i3 * D_ + dd];
        *reinterpret_cast<float4*>(obase + (size_t)dd * HW_ + (m4 << 2)) = o;
    }
}

extern "C" void kernel_launch(void* const* d_in, const int* in_sizes, int n_in,
                              void* d_out, int out_size, void* d_ws, size_t ws_size,
                              hipStream_t stream) {
    const float* z  = (const float*)d_in[0];   // 16*256*32*32
    const float* cb = (const float*)d_in[1];   // 2048*256
    float* pscore = (float*)d_ws;                       // 4*16384
    int*   pidx   = (int*)(pscore + SPLIT * NPIX);      // 4*16384
    float* An     = (float*)(pidx + SPLIT * NPIX);      // 16384
    float* Bn     = An + NPIX;                          // 2048
    float* ct     = Bn + K_;                            // 256*2048 (2 MB)
    float* out    = (float*)d_out;

    prep_k<<<dim3(200), dim3(256), 0, stream>>>(z, cb, ct, An, Bn);
    vq_k<<<dim3(128 * SPLIT), dim3(512), 0, stream>>>(z, ct, An, Bn, pscore, pidx);
    fin_k<<<dim3(256), dim3(256), 0, stream>>>(cb, pscore, pidx, out);
}